// Round 11
// baseline (207.208 us; speedup 1.0000x reference)
//
#include <hip/hip_runtime.h>
#include <hip/hip_bf16.h>

// ---------------------------------------------------------------------------
// B=2, S=2048, D=768, H=12, Dh=64. M = B*S = 4096.
// R11: (1) Both GEMMs BK=64 (half the barrier drains; 32 MFMA/wave/iter).
// (2) transpose_v fused into qkv epilogue: seg==2 writes VT[b][h][d][s]
// directly (4 contiguous tokens per uint2 store; L2 coalesces lines).
// (3) 4 dispatches. attn frozen at R10 (LDS-pipe-bound, 68.2 us).
// ---------------------------------------------------------------------------

typedef __attribute__((ext_vector_type(8))) short short8;   // 8 x bf16 (4 VGPR)
typedef __attribute__((ext_vector_type(4))) float float4e;  // 4 x fp32 acc

__device__ __forceinline__ ushort f2bf(float f) {
    union { float f; unsigned u; } v; v.f = f;
    unsigned r = v.u + 0x7FFF + ((v.u >> 16) & 1);
    return (ushort)(r >> 16);
}

// packed RNE fp32x2 -> bf16x2 (v_cvt_pk_bf16_f32); low 16 bits = first arg
__device__ __forceinline__ unsigned pk2bf(float a, float b) {
    float2 t; t.x = a; t.y = b;
    __hip_bfloat162 h = __float22bfloat162_rn(t);
    union { __hip_bfloat162 h; unsigned u; } cv; cv.h = h;
    return cv.u;
}

// async 16B global -> LDS; LDS dest = wave-uniform base + lane*16.
__device__ __forceinline__ void async_cp16(const ushort* g, ushort* l) {
    __builtin_amdgcn_global_load_lds(
        (const __attribute__((address_space(1))) unsigned int*)g,
        (__attribute__((address_space(3))) unsigned int*)l,
        16, 0, 0);
}

// ===========================================================================
// Prep: z = 0..3 -> transpose+cast W[z]; z = 4 -> grid-stride cast x.
// ===========================================================================
__global__ __launch_bounds__(256) void prep_cast(
    const float* __restrict__ x, ushort* __restrict__ xb,
    const float* __restrict__ W0, const float* __restrict__ W1,
    const float* __restrict__ W2, const float* __restrict__ W3,
    ushort* __restrict__ WtBase)
{
    __shared__ float t[64][65];
    const int z = blockIdx.z;
    const int tid = threadIdx.x;

    if (z == 4) {                       // x cast: 144 blocks, grid-stride
        const int nblk = gridDim.x * gridDim.y;
        const int bid  = blockIdx.y * gridDim.x + blockIdx.x;
        const int n4   = 4096 * 768 / 4;
        for (int i = bid * 256 + tid; i < n4; i += nblk * 256) {
            float4 v = *(const float4*)&x[(size_t)i * 4];
            ushort4 o;
            o.x = f2bf(v.x); o.y = f2bf(v.y); o.z = f2bf(v.z); o.w = f2bf(v.w);
            *(ushort4*)&xb[(size_t)i * 4] = o;
        }
        return;
    }

    const float* W = (z == 0) ? W0 : (z == 1) ? W1 : (z == 2) ? W2 : W3;
    ushort* Wt = WtBase + (size_t)z * (768u * 768u);
    const int c  = tid & 63;
    const int rg = tid >> 6;
    const int k0 = blockIdx.y * 64, n0 = blockIdx.x * 64;
    #pragma unroll
    for (int r = 0; r < 16; ++r) {
        const int row = rg * 16 + r;
        t[row][c] = W[(size_t)(k0 + row) * 768 + n0 + c];
    }
    __syncthreads();
    #pragma unroll
    for (int r = 0; r < 16; ++r) {
        const int row = rg * 16 + r;
        Wt[(size_t)(n0 + row) * 768 + k0 + c] = f2bf(t[c][row]);
    }
}

// ===========================================================================
// Fused QKV GEMM: x[M,768] @ [Wq|Wk|Wv]^T + bias. 128x128 tile, BK=64,
// async staging (4 issues/wave/matrix/iter). seg 0/1 (Q,K) -> token-major
// qb/kb; seg 2 (V) -> VT[b][h][d][s] transposed (kills transpose_v kernel).
// ===========================================================================
__global__ __launch_bounds__(256) void gemm_qkv_fused(
    const ushort* __restrict__ A, const ushort* __restrict__ Bt,
    const float* __restrict__ bq, const float* __restrict__ bk,
    const float* __restrict__ bv, ushort* __restrict__ Outbase,
    ushort* __restrict__ VTout)
{
    constexpr int K = 768;
    __shared__ ushort As[128][64];   // 16 KB, unpadded (global_load_lds)
    __shared__ ushort Bs[128][64];

    const int tid  = threadIdx.x;
    const int w    = tid >> 6;
    const int lane = tid & 63;
    const int l16  = lane & 15;
    const int quad = lane >> 4;
    const int wr   = (w >> 1) * 64;
    const int wc   = (w & 1) * 64;
    const int row0 = blockIdx.y * 128, col0 = blockIdx.x * 128;

    // staging: issue i covers rows w*32+i*8 + (lane>>3), col (lane&7)*8;
    // LDS offset = (lane>>3)*128B + (lane&7)*16B = lane*16 (rule satisfied)
    const int r8 = lane >> 3;
    const int c8 = (lane & 7) * 8;

    float4e acc[4][4];
    #pragma unroll
    for (int mi = 0; mi < 4; ++mi)
        #pragma unroll
        for (int ni = 0; ni < 4; ++ni) acc[mi][ni] = (float4e){0.f,0.f,0.f,0.f};

    for (int k0 = 0; k0 < K; k0 += 64) {
        #pragma unroll
        for (int i = 0; i < 4; ++i) {
            const int rr = w * 32 + i * 8;
            async_cp16(&A [(size_t)(row0 + rr + r8) * K + k0 + c8], &As[rr][0]);
            async_cp16(&Bt[(size_t)(col0 + rr + r8) * K + k0 + c8], &Bs[rr][0]);
        }
        __syncthreads();   // drains vmcnt

        #pragma unroll
        for (int kk = 0; kk < 2; ++kk) {
            short8 af[4], bf[4];
            #pragma unroll
            for (int i = 0; i < 4; ++i) {
                af[i] = *(const short8*)&As[wr + i * 16 + l16][kk * 32 + quad * 8];
                bf[i] = *(const short8*)&Bs[wc + i * 16 + l16][kk * 32 + quad * 8];
            }
            #pragma unroll
            for (int mi = 0; mi < 4; ++mi)
                #pragma unroll
                for (int ni = 0; ni < 4; ++ni)
                    acc[mi][ni] = __builtin_amdgcn_mfma_f32_16x16x32_bf16(
                        af[mi], bf[ni], acc[mi][ni], 0, 0, 0);
        }
        __syncthreads();
    }

    const int seg = (col0 >= 1536) ? 2 : (col0 >= 768 ? 1 : 0);
    const float* bias = (seg == 0) ? bq : (seg == 1) ? bk : bv;
    const int ncol0 = col0 - seg * 768 + wc;

    if (seg == 2) {
        // V: write transposed VT[(b*12+h)*64+d][s], 4 tokens per uint2
        #pragma unroll
        for (int ni = 0; ni < 4; ++ni) {
            const int col = ncol0 + ni * 16 + l16;   // 0..767
            const int h2 = col >> 6, d = col & 63;
            const float bs = bias[col];
            #pragma unroll
            for (int mi = 0; mi < 4; ++mi) {
                const int trow = row0 + wr + mi * 16 + quad * 4; // global token
                const int b2 = trow >> 11, s = trow & 2047;
                uint2 ov;
                ov.x = pk2bf(acc[mi][ni][0] + bs, acc[mi][ni][1] + bs);
                ov.y = pk2bf(acc[mi][ni][2] + bs, acc[mi][ni][3] + bs);
                *(uint2*)&VTout[((size_t)(b2 * 12 + h2) * 64 + d) * 2048 + s] = ov;
            }
        }
    } else {
        ushort* outp = Outbase + (size_t)seg * (4096u * 768u);
        #pragma unroll
        for (int ni = 0; ni < 4; ++ni) {
            const int col = ncol0 + ni * 16 + l16;
            const float bs = bias[col];
            #pragma unroll
            for (int mi = 0; mi < 4; ++mi) {
                #pragma unroll
                for (int r = 0; r < 4; ++r) {
                    const int row = row0 + wr + mi * 16 + quad * 4 + r;
                    outp[(size_t)row * 768 + col] = f2bf(acc[mi][ni][r] + bs);
                }
            }
        }
    }
}

// ===========================================================================
// Wo GEMM: C[4096,768](fp32) = ctx @ Wo^T + bo. 128x128 tile, BK=64,
// async staging.
// ===========================================================================
__global__ __launch_bounds__(256) void gemm_wo_128(
    const ushort* __restrict__ A, const ushort* __restrict__ Bt,
    const float* __restrict__ bias, float* __restrict__ Cout)
{
    constexpr int K = 768, N = 768;
    __shared__ ushort As[128][64];
    __shared__ ushort Bs[128][64];

    const int tid  = threadIdx.x;
    const int w    = tid >> 6;
    const int lane = tid & 63;
    const int l16  = lane & 15;
    const int quad = lane >> 4;
    const int wr   = (w >> 1) * 64;
    const int wc   = (w & 1) * 64;
    const int row0 = blockIdx.y * 128, col0 = blockIdx.x * 128;

    const int r8 = lane >> 3;
    const int c8 = (lane & 7) * 8;

    float4e acc[4][4];
    #pragma unroll
    for (int mi = 0; mi < 4; ++mi)
        #pragma unroll
        for (int ni = 0; ni < 4; ++ni) acc[mi][ni] = (float4e){0.f,0.f,0.f,0.f};

    for (int k0 = 0; k0 < K; k0 += 64) {
        #pragma unroll
        for (int i = 0; i < 4; ++i) {
            const int rr = w * 32 + i * 8;
            async_cp16(&A [(size_t)(row0 + rr + r8) * K + k0 + c8], &As[rr][0]);
            async_cp16(&Bt[(size_t)(col0 + rr + r8) * K + k0 + c8], &Bs[rr][0]);
        }
        __syncthreads();

        #pragma unroll
        for (int kk = 0; kk < 2; ++kk) {
            short8 af[4], bf[4];
            #pragma unroll
            for (int i = 0; i < 4; ++i) {
                af[i] = *(const short8*)&As[wr + i * 16 + l16][kk * 32 + quad * 8];
                bf[i] = *(const short8*)&Bs[wc + i * 16 + l16][kk * 32 + quad * 8];
            }
            #pragma unroll
            for (int mi = 0; mi < 4; ++mi)
                #pragma unroll
                for (int ni = 0; ni < 4; ++ni)
                    acc[mi][ni] = __builtin_amdgcn_mfma_f32_16x16x32_bf16(
                        af[mi], bf[ni], acc[mi][ni], 0, 0, 0);
        }
        __syncthreads();
    }

    #pragma unroll
    for (int ni = 0; ni < 4; ++ni) {
        const int col = col0 + wc + ni * 16 + l16;
        const float bs = bias[col];
        #pragma unroll
        for (int mi = 0; mi < 4; ++mi) {
            #pragma unroll
            for (int r = 0; r < 4; ++r) {
                const int row = row0 + wr + mi * 16 + quad * 4 + r;
                Cout[(size_t)row * N + col] = acc[mi][ni][r] + bs;
            }
        }
    }
}

// ===========================================================================
// Flash attention, S^T formulation, TK=64 (frozen R10: 68.2 us).
// ===========================================================================
__global__ __launch_bounds__(256) void attn_mfma(
    const ushort* __restrict__ Qg, const ushort* __restrict__ Kgl,
    const ushort* __restrict__ VT, ushort* __restrict__ Ctx)
{
    constexpr int S = 2048, D = 768;
    __shared__ ushort Ks [64][72];   // [key][d]
    __shared__ ushort Vts[64][72];   // [d][key]
    __shared__ ushort Ps [64][72];   // [w*16+query][key]

    const int tid  = threadIdx.x;
    const int w    = tid >> 6;
    const int lane = tid & 63;
    const int l16  = lane & 15;
    const int quad = lane >> 4;
    const int b = blockIdx.z, h = blockIdx.y, q0 = blockIdx.x * 64;
    const size_t hc = (size_t)h * 64;

    const size_t qoff = (size_t)(b * S + q0 + w * 16 + l16) * D + hc + quad * 8;
    const short8 yq0 = *(const short8*)&Qg[qoff];
    const short8 yq1 = *(const short8*)&Qg[qoff + 32];

    float m_ = -1e30f, l_ = 0.f;
    float4e oa[4];
    #pragma unroll
    for (int n = 0; n < 4; ++n) oa[n] = (float4e){0.f, 0.f, 0.f, 0.f};

    const int sr = tid >> 2;          // key row (Ks) / head-dim (Vts)
    const int sc = (tid & 3) * 16;
    const size_t vtb = ((size_t)(b * 12 + h) * 64 + sr) * 2048;

    uint4 kA, kB, vA, vB;
    {
        const size_t gk = (size_t)(b * S + sr) * D + hc + sc;
        kA = *(const uint4*)&Kgl[gk];
        kB = *(const uint4*)&Kgl[gk + 8];
        vA = *(const uint4*)&VT[vtb + sc];
        vB = *(const uint4*)&VT[vtb + sc + 8];
    }

    for (int k0 = 0; k0 < S; k0 += 64) {
        *(uint4*)&Ks [sr][sc    ] = kA;
        *(uint4*)&Ks [sr][sc + 8] = kB;
        *(uint4*)&Vts[sr][sc    ] = vA;
        *(uint4*)&Vts[sr][sc + 8] = vB;
        __syncthreads();

        if (k0 + 64 < S) {
            const size_t gk = (size_t)(b * S + k0 + 64 + sr) * D + hc + sc;
            kA = *(const uint4*)&Kgl[gk];
            kB = *(const uint4*)&Kgl[gk + 8];
            vA = *(const uint4*)&VT[vtb + k0 + 64 + sc];
            vB = *(const uint4*)&VT[vtb + k0 + 64 + sc + 8];
        }

        // ---- S^T: lane gets S[query=l16][key=kb*16+quad*4+r] ----
        float4e sa[4];
        #pragma unroll
        for (int kb = 0; kb < 4; ++kb) {
            const short8 xk0 = *(const short8*)&Ks[kb * 16 + l16][quad * 8];
            const short8 xk1 = *(const short8*)&Ks[kb * 16 + l16][32 + quad * 8];
            float4e z = (float4e){0.f, 0.f, 0.f, 0.f};
            z      = __builtin_amdgcn_mfma_f32_16x16x32_bf16(xk0, yq0, z, 0, 0, 0);
            sa[kb] = __builtin_amdgcn_mfma_f32_16x16x32_bf16(xk1, yq1, z, 0, 0, 0);
        }

        // ---- online softmax: 16 vals in-lane + 2 cross-quad shuffles ----
        float mx = -1e30f;
        #pragma unroll
        for (int kb = 0; kb < 4; ++kb)
            #pragma unroll
            for (int r = 0; r < 4; ++r) mx = fmaxf(mx, sa[kb][r]);
        mx = fmaxf(mx, __shfl_xor(mx, 16, 64));
        mx = fmaxf(mx, __shfl_xor(mx, 32, 64));
        const float mn = fmaxf(m_, mx);
        const float alpha = __expf(m_ - mn);    // first iter: 0
        float p[4][4], ps = 0.f;
        #pragma unroll
        for (int kb = 0; kb < 4; ++kb)
            #pragma unroll
            for (int r = 0; r < 4; ++r) {
                p[kb][r] = __expf(sa[kb][r] - mn);
                ps += p[kb][r];
            }
        ps += __shfl_xor(ps, 16, 64);
        ps += __shfl_xor(ps, 32, 64);
        l_ = l_ * alpha + ps;
        m_ = mn;

        // ---- P -> LDS: packed cvt, 4 keys per 8B write ----
        #pragma unroll
        for (int kb = 0; kb < 4; ++kb) {
            uint2 pk;
            pk.x = pk2bf(p[kb][0], p[kb][1]);
            pk.y = pk2bf(p[kb][2], p[kb][3]);
            *(uint2*)&Ps[w * 16 + l16][kb * 16 + quad * 4] = pk;
        }

        // ---- rescale O^T and accumulate PV ----
        #pragma unroll
        for (int n = 0; n < 4; ++n)
            #pragma unroll
            for (int r = 0; r < 4; ++r) oa[n][r] *= alpha;

        const short8 yp0 = *(const short8*)&Ps[w * 16 + l16][quad * 8];
        const short8 yp1 = *(const short8*)&Ps[w * 16 + l16][32 + quad * 8];
        #pragma unroll
        for (int db = 0; db < 4; ++db) {
            const short8 xv0 = *(const short8*)&Vts[db * 16 + l16][quad * 8];
            const short8 xv1 = *(const short8*)&Vts[db * 16 + l16][32 + quad * 8];
            oa[db] = __builtin_amdgcn_mfma_f32_16x16x32_bf16(xv0, yp0, oa[db], 0, 0, 0);
            oa[db] = __builtin_amdgcn_mfma_f32_16x16x32_bf16(xv1, yp1, oa[db], 0, 0, 0);
        }
        __syncthreads();
    }

    // ---- normalize, write ctx (packed cvt) ----
    const float inv = 1.0f / l_;
    const size_t crow = (size_t)(b * S + q0 + w * 16 + l16) * D + hc;
    #pragma unroll
    for (int db = 0; db < 4; ++db) {
        uint2 ov;
        ov.x = pk2bf(oa[db][0] * inv, oa[db][1] * inv);
        ov.y = pk2bf(oa[db][2] * inv, oa[db][3] * inv);
        *(uint2*)&Ctx[crow + db * 16 + quad * 4] = ov;
    }
}

// ===========================================================================
// Launch: prep -> fused QKV (V written transposed) -> attn -> Wo. 4 dispatches.
// ===========================================================================
extern "C" void kernel_launch(void* const* d_in, const int* in_sizes, int n_in,
                              void* d_out, int out_size, void* d_ws, size_t ws_size,
                              hipStream_t stream)
{
    const float* x  = (const float*)d_in[0];
    const float* Wq = (const float*)d_in[1];
    const float* bq = (const float*)d_in[2];
    const float* Wk = (const float*)d_in[3];
    const float* bk = (const float*)d_in[4];
    const float* Wv = (const float*)d_in[5];
    const float* bv = (const float*)d_in[6];
    const float* Wo = (const float*)d_in[7];
    const float* bo = (const float*)d_in[8];

    const int M = 4096, D = 768;
    const size_t XE = (size_t)M * D;     // 3,145,728
    const size_t WE = (size_t)D * D;     //   589,824

    ushort* xb   = (ushort*)d_ws;
    ushort* wtq  = xb   + XE;            // wtq/wtk/wtv/wto contiguous
    ushort* wto  = wtq  + 3 * WE;
    ushort* qb   = wto  + WE;            // qb/kb contiguous (seg 0/1)
    ushort* kb   = qb   + XE;
    ushort* vt   = kb   + XE;            // V lands here TRANSPOSED (seg 2)
    ushort* ctxb = vt   + XE;

    prep_cast<<<dim3(12, 12, 5), 256, 0, stream>>>(x, xb, Wq, Wk, Wv, Wo, wtq);

    gemm_qkv_fused<<<dim3(2304 / 128, 4096 / 128), 256, 0, stream>>>(
        xb, wtq, bq, bk, bv, qb, vt);

    attn_mfma<<<dim3(2048 / 64, 12, 2), 256, 0, stream>>>(qb, kb, vt, ctxb);

    gemm_wo_128<<<dim3(768 / 128, 4096 / 128), 256, 0, stream>>>(
        ctxb, wto, bo, (float*)d_out);
}

// Round 12
// 195.839 us; speedup vs baseline: 1.0581x; 1.0581x over previous
//
#include <hip/hip_runtime.h>
#include <hip/hip_bf16.h>

// ---------------------------------------------------------------------------
// B=2, S=2048, D=768, H=12, Dh=64. M = B*S = 4096.
// R12: best-known-components build. Exactly R9's pipeline (194.7 us:
// separate cast + w4 transpose, qkv BK=32 async global_load_lds,
// standalone transpose_v, wo 128-tile register-prefetch) with ONE change:
// attn uses R10's packed v_cvt_pk_bf16_f32 (isolated -1.3 us, 68.2 us).
// R11's BK=64 + fused-VT epilogue regressed (+9 us) -> reverted.
// attn redesigns needing >68 VGPR are dead (R7/R8: allocator pins & spills).
// ---------------------------------------------------------------------------

typedef __attribute__((ext_vector_type(8))) short short8;   // 8 x bf16 (4 VGPR)
typedef __attribute__((ext_vector_type(4))) float float4e;  // 4 x fp32 acc

__device__ __forceinline__ ushort f2bf(float f) {
    union { float f; unsigned u; } v; v.f = f;
    unsigned r = v.u + 0x7FFF + ((v.u >> 16) & 1);
    return (ushort)(r >> 16);
}

// packed RNE fp32x2 -> bf16x2 (v_cvt_pk_bf16_f32); low 16 bits = first arg
__device__ __forceinline__ unsigned pk2bf(float a, float b) {
    float2 t; t.x = a; t.y = b;
    __hip_bfloat162 h = __float22bfloat162_rn(t);
    union { __hip_bfloat162 h; unsigned u; } cv; cv.h = h;
    return cv.u;
}

// async 16B global -> LDS; LDS dest = wave-uniform base + lane*16.
__device__ __forceinline__ void async_cp16(const ushort* g, ushort* l) {
    __builtin_amdgcn_global_load_lds(
        (const __attribute__((address_space(1))) unsigned int*)g,
        (__attribute__((address_space(3))) unsigned int*)l,
        16, 0, 0);
}

// ===========================================================================
// x [4096x768] fp32 -> bf16
// ===========================================================================
__global__ __launch_bounds__(256) void cast_f32_bf16(
    const float* __restrict__ in, ushort* __restrict__ out, int n4)
{
    int i = blockIdx.x * blockDim.x + threadIdx.x;
    if (i < n4) {
        float4 v = *(const float4*)&in[(size_t)i * 4];
        ushort4 o;
        o.x = f2bf(v.x); o.y = f2bf(v.y); o.z = f2bf(v.z); o.w = f2bf(v.w);
        *(ushort4*)&out[(size_t)i * 4] = o;
    }
}

// ===========================================================================
// All 4 weight transposes in one launch: z selects Wq/Wk/Wv/Wo.
// ===========================================================================
__global__ __launch_bounds__(256) void transpose_cast_w4(
    const float* __restrict__ W0, const float* __restrict__ W1,
    const float* __restrict__ W2, const float* __restrict__ W3,
    ushort* __restrict__ WtBase)
{
    __shared__ float t[64][65];
    const int z = blockIdx.z;
    const float* W = (z == 0) ? W0 : (z == 1) ? W1 : (z == 2) ? W2 : W3;
    ushort* Wt = WtBase + (size_t)z * (768u * 768u);

    const int tid = threadIdx.x;
    const int c  = tid & 63;
    const int rg = tid >> 6;
    const int k0 = blockIdx.y * 64, n0 = blockIdx.x * 64;
    #pragma unroll
    for (int r = 0; r < 16; ++r) {
        const int row = rg * 16 + r;
        t[row][c] = W[(size_t)(k0 + row) * 768 + n0 + c];
    }
    __syncthreads();
    #pragma unroll
    for (int r = 0; r < 16; ++r) {
        const int row = rg * 16 + r;
        Wt[(size_t)(n0 + row) * 768 + k0 + c] = f2bf(t[c][row]);
    }
}

// ===========================================================================
// V [4096x768] bf16 -> VT[b][h][d][s] bf16 (s-major per head).
// ===========================================================================
__global__ __launch_bounds__(256) void transpose_v(
    const ushort* __restrict__ Vb, ushort* __restrict__ VT)
{
    __shared__ ushort t[64][72];
    const int tid = threadIdx.x;
    const int b = blockIdx.z, h = blockIdx.y, s0 = blockIdx.x * 64;
    const int lr = tid >> 3;          // 0..31
    const int lc = (tid & 7) * 8;     // 0..56

    #pragma unroll
    for (int half = 0; half < 64; half += 32) {
        const int row = lr + half;
        *(uint4*)&t[row][lc] =
            *(const uint4*)&Vb[(size_t)(b * 2048 + s0 + row) * 768 + h * 64 + lc];
    }
    __syncthreads();
    #pragma unroll
    for (int half = 0; half < 64; half += 32) {
        const int d = lr + half;
        ushort tmp[8];
        #pragma unroll
        for (int i = 0; i < 8; ++i) tmp[i] = t[lc + i][d];
        *(uint4*)&VT[((size_t)(b * 12 + h) * 64 + d) * 2048 + s0 + lc] =
            *(const uint4*)tmp;
    }
}

// ===========================================================================
// Fused QKV GEMM: Out[M,2304] = x[M,768] @ [Wq|Wk|Wv]^T + [bq|bk|bv]
// 128x128 tile, BK=32, 4 waves 2x2, 16 accs/wave; m97-style async staging.
// (R9 verbatim — the best-measured GEMM config.)
// ===========================================================================
__global__ __launch_bounds__(256) void gemm_qkv_fused(
    const ushort* __restrict__ A, const ushort* __restrict__ Bt,
    const float* __restrict__ bq, const float* __restrict__ bk,
    const float* __restrict__ bv, ushort* __restrict__ Outbase)
{
    constexpr int K = 768;
    __shared__ ushort As[128][32];   // unpadded: required by global_load_lds
    __shared__ ushort Bs[128][32];

    const int tid  = threadIdx.x;
    const int w    = tid >> 6;
    const int lane = tid & 63;
    const int l16  = lane & 15;
    const int quad = lane >> 4;
    const int wr   = (w >> 1) * 64;
    const int wc   = (w & 1) * 64;
    const int row0 = blockIdx.y * 128, col0 = blockIdx.x * 128;

    const int r4 = lane >> 2;
    const int c8 = (lane & 3) * 8;

    float4e acc[4][4];
    #pragma unroll
    for (int mi = 0; mi < 4; ++mi)
        #pragma unroll
        for (int ni = 0; ni < 4; ++ni) acc[mi][ni] = (float4e){0.f,0.f,0.f,0.f};

    for (int k0 = 0; k0 < K; k0 += 32) {
        #pragma unroll
        for (int i = 0; i < 2; ++i) {
            const int rr = w * 32 + i * 16;
            async_cp16(&A [(size_t)(row0 + rr + r4) * K + k0 + c8], &As[rr][0]);
            async_cp16(&Bt[(size_t)(col0 + rr + r4) * K + k0 + c8], &Bs[rr][0]);
        }
        __syncthreads();   // drains vmcnt -> staged data visible

        short8 af[4], bf[4];
        #pragma unroll
        for (int i = 0; i < 4; ++i) {
            af[i] = *(const short8*)&As[wr + i * 16 + l16][quad * 8];
            bf[i] = *(const short8*)&Bs[wc + i * 16 + l16][quad * 8];
        }
        #pragma unroll
        for (int mi = 0; mi < 4; ++mi)
            #pragma unroll
            for (int ni = 0; ni < 4; ++ni)
                acc[mi][ni] = __builtin_amdgcn_mfma_f32_16x16x32_bf16(
                    af[mi], bf[ni], acc[mi][ni], 0, 0, 0);
        __syncthreads();
    }

    const int seg = (col0 >= 1536) ? 2 : (col0 >= 768 ? 1 : 0);
    const float* bias = (seg == 0) ? bq : (seg == 1) ? bk : bv;
    const int ncol0 = col0 - seg * 768 + wc;
    ushort* outp = Outbase + (size_t)seg * (4096u * 768u);

    #pragma unroll
    for (int ni = 0; ni < 4; ++ni) {
        const int col = ncol0 + ni * 16 + l16;
        const float bs = bias[col];
        #pragma unroll
        for (int mi = 0; mi < 4; ++mi) {
            #pragma unroll
            for (int r = 0; r < 4; ++r) {
                const int row = row0 + wr + mi * 16 + quad * 4 + r;
                outp[(size_t)row * 768 + col] = f2bf(acc[mi][ni][r] + bs);
            }
        }
    }
}

// ===========================================================================
// Wo GEMM: C[4096,768](fp32) = ctx[4096,768] @ Wo^T + bo. 128x128 tile,
// register-prefetch staging (R9 verbatim).
// ===========================================================================
__global__ __launch_bounds__(256) void gemm_wo_128(
    const ushort* __restrict__ A, const ushort* __restrict__ Bt,
    const float* __restrict__ bias, float* __restrict__ Cout)
{
    constexpr int K = 768, N = 768;
    __shared__ ushort As[128][40];
    __shared__ ushort Bs[128][40];

    const int tid  = threadIdx.x;
    const int w    = tid >> 6;
    const int lane = tid & 63;
    const int l16  = lane & 15;
    const int quad = lane >> 4;
    const int wr   = (w >> 1) * 64;
    const int wc   = (w & 1) * 64;
    const int row0 = blockIdx.y * 128, col0 = blockIdx.x * 128;
    const int sr = tid >> 2, sc = (tid & 3) * 8;

    float4e acc[4][4];
    #pragma unroll
    for (int mi = 0; mi < 4; ++mi)
        #pragma unroll
        for (int ni = 0; ni < 4; ++ni) acc[mi][ni] = (float4e){0.f,0.f,0.f,0.f};

    uint4 a0 = *(const uint4*)&A [(size_t)(row0 + sr     ) * K + sc];
    uint4 a1 = *(const uint4*)&A [(size_t)(row0 + sr + 64) * K + sc];
    uint4 b0 = *(const uint4*)&Bt[(size_t)(col0 + sr     ) * K + sc];
    uint4 b1 = *(const uint4*)&Bt[(size_t)(col0 + sr + 64) * K + sc];

    for (int k0 = 0; k0 < K; k0 += 32) {
        *(uint4*)&As[sr     ][sc] = a0;
        *(uint4*)&As[sr + 64][sc] = a1;
        *(uint4*)&Bs[sr     ][sc] = b0;
        *(uint4*)&Bs[sr + 64][sc] = b1;
        __syncthreads();

        if (k0 + 32 < K) {
            const int kn = k0 + 32;
            a0 = *(const uint4*)&A [(size_t)(row0 + sr     ) * K + kn + sc];
            a1 = *(const uint4*)&A [(size_t)(row0 + sr + 64) * K + kn + sc];
            b0 = *(const uint4*)&Bt[(size_t)(col0 + sr     ) * K + kn + sc];
            b1 = *(const uint4*)&Bt[(size_t)(col0 + sr + 64) * K + kn + sc];
        }

        short8 af[4], bf[4];
        #pragma unroll
        for (int i = 0; i < 4; ++i) {
            af[i] = *(const short8*)&As[wr + i * 16 + l16][quad * 8];
            bf[i] = *(const short8*)&Bs[wc + i * 16 + l16][quad * 8];
        }
        #pragma unroll
        for (int mi = 0; mi < 4; ++mi)
            #pragma unroll
            for (int ni = 0; ni < 4; ++ni)
                acc[mi][ni] = __builtin_amdgcn_mfma_f32_16x16x32_bf16(
                    af[mi], bf[ni], acc[mi][ni], 0, 0, 0);
        __syncthreads();
    }

    #pragma unroll
    for (int ni = 0; ni < 4; ++ni) {
        const int col = col0 + wc + ni * 16 + l16;
        const float bs = bias[col];
        #pragma unroll
        for (int mi = 0; mi < 4; ++mi) {
            #pragma unroll
            for (int r = 0; r < 4; ++r) {
                const int row = row0 + wr + mi * 16 + quad * 4 + r;
                Cout[(size_t)row * N + col] = acc[mi][ni][r] + bs;
            }
        }
    }
}

// ===========================================================================
// Flash attention, S^T formulation, TK=64, packed-cvt (R10 verbatim:
// 68.2 us, VGPR 52, no spill, LDS-pipe-bound).
// ===========================================================================
__global__ __launch_bounds__(256) void attn_mfma(
    const ushort* __restrict__ Qg, const ushort* __restrict__ Kgl,
    const ushort* __restrict__ VT, ushort* __restrict__ Ctx)
{
    constexpr int S = 2048, D = 768;
    __shared__ ushort Ks [64][72];   // [key][d]
    __shared__ ushort Vts[64][72];   // [d][key]
    __shared__ ushort Ps [64][72];   // [w*16+query][key]

    const int tid  = threadIdx.x;
    const int w    = tid >> 6;
    const int lane = tid & 63;
    const int l16  = lane & 15;
    const int quad = lane >> 4;
    const int b = blockIdx.z, h = blockIdx.y, q0 = blockIdx.x * 64;
    const size_t hc = (size_t)h * 64;

    const size_t qoff = (size_t)(b * S + q0 + w * 16 + l16) * D + hc + quad * 8;
    const short8 yq0 = *(const short8*)&Qg[qoff];
    const short8 yq1 = *(const short8*)&Qg[qoff + 32];

    float m_ = -1e30f, l_ = 0.f;
    float4e oa[4];
    #pragma unroll
    for (int n = 0; n < 4; ++n) oa[n] = (float4e){0.f, 0.f, 0.f, 0.f};

    const int sr = tid >> 2;          // key row (Ks) / head-dim (Vts)
    const int sc = (tid & 3) * 16;
    const size_t vtb = ((size_t)(b * 12 + h) * 64 + sr) * 2048;

    uint4 kA, kB, vA, vB;
    {
        const size_t gk = (size_t)(b * S + sr) * D + hc + sc;
        kA = *(const uint4*)&Kgl[gk];
        kB = *(const uint4*)&Kgl[gk + 8];
        vA = *(const uint4*)&VT[vtb + sc];
        vB = *(const uint4*)&VT[vtb + sc + 8];
    }

    for (int k0 = 0; k0 < S; k0 += 64) {
        *(uint4*)&Ks [sr][sc    ] = kA;
        *(uint4*)&Ks [sr][sc + 8] = kB;
        *(uint4*)&Vts[sr][sc    ] = vA;
        *(uint4*)&Vts[sr][sc + 8] = vB;
        __syncthreads();

        if (k0 + 64 < S) {
            const size_t gk = (size_t)(b * S + k0 + 64 + sr) * D + hc + sc;
            kA = *(const uint4*)&Kgl[gk];
            kB = *(const uint4*)&Kgl[gk + 8];
            vA = *(const uint4*)&VT[vtb + k0 + 64 + sc];
            vB = *(const uint4*)&VT[vtb + k0 + 64 + sc + 8];
        }

        // ---- S^T: lane gets S[query=l16][key=kb*16+quad*4+r] ----
        float4e sa[4];
        #pragma unroll
        for (int kb = 0; kb < 4; ++kb) {
            const short8 xk0 = *(const short8*)&Ks[kb * 16 + l16][quad * 8];
            const short8 xk1 = *(const short8*)&Ks[kb * 16 + l16][32 + quad * 8];
            float4e z = (float4e){0.f, 0.f, 0.f, 0.f};
            z      = __builtin_amdgcn_mfma_f32_16x16x32_bf16(xk0, yq0, z, 0, 0, 0);
            sa[kb] = __builtin_amdgcn_mfma_f32_16x16x32_bf16(xk1, yq1, z, 0, 0, 0);
        }

        // ---- online softmax: 16 vals in-lane + 2 cross-quad shuffles ----
        float mx = -1e30f;
        #pragma unroll
        for (int kb = 0; kb < 4; ++kb)
            #pragma unroll
            for (int r = 0; r < 4; ++r) mx = fmaxf(mx, sa[kb][r]);
        mx = fmaxf(mx, __shfl_xor(mx, 16, 64));
        mx = fmaxf(mx, __shfl_xor(mx, 32, 64));
        const float mn = fmaxf(m_, mx);
        const float alpha = __expf(m_ - mn);    // first iter: 0
        float p[4][4], ps = 0.f;
        #pragma unroll
        for (int kb = 0; kb < 4; ++kb)
            #pragma unroll
            for (int r = 0; r < 4; ++r) {
                p[kb][r] = __expf(sa[kb][r] - mn);
                ps += p[kb][r];
            }
        ps += __shfl_xor(ps, 16, 64);
        ps += __shfl_xor(ps, 32, 64);
        l_ = l_ * alpha + ps;
        m_ = mn;

        // ---- P -> LDS: packed cvt, 4 keys per 8B write ----
        #pragma unroll
        for (int kb = 0; kb < 4; ++kb) {
            uint2 pk;
            pk.x = pk2bf(p[kb][0], p[kb][1]);
            pk.y = pk2bf(p[kb][2], p[kb][3]);
            *(uint2*)&Ps[w * 16 + l16][kb * 16 + quad * 4] = pk;
        }

        // ---- rescale O^T and accumulate PV ----
        #pragma unroll
        for (int n = 0; n < 4; ++n)
            #pragma unroll
            for (int r = 0; r < 4; ++r) oa[n][r] *= alpha;

        const short8 yp0 = *(const short8*)&Ps[w * 16 + l16][quad * 8];
        const short8 yp1 = *(const short8*)&Ps[w * 16 + l16][32 + quad * 8];
        #pragma unroll
        for (int db = 0; db < 4; ++db) {
            const short8 xv0 = *(const short8*)&Vts[db * 16 + l16][quad * 8];
            const short8 xv1 = *(const short8*)&Vts[db * 16 + l16][32 + quad * 8];
            oa[db] = __builtin_amdgcn_mfma_f32_16x16x32_bf16(xv0, yp0, oa[db], 0, 0, 0);
            oa[db] = __builtin_amdgcn_mfma_f32_16x16x32_bf16(xv1, yp1, oa[db], 0, 0, 0);
        }
        __syncthreads();
    }

    // ---- normalize, write ctx (packed cvt) ----
    const float inv = 1.0f / l_;
    const size_t crow = (size_t)(b * S + q0 + w * 16 + l16) * D + hc;
    #pragma unroll
    for (int db = 0; db < 4; ++db) {
        uint2 ov;
        ov.x = pk2bf(oa[db][0] * inv, oa[db][1] * inv);
        ov.y = pk2bf(oa[db][2] * inv, oa[db][3] * inv);
        *(uint2*)&Ctx[crow + db * 16 + quad * 4] = ov;
    }
}

// ===========================================================================
// Launch (R9 pipeline shape: 6 dispatches)
// ===========================================================================
extern "C" void kernel_launch(void* const* d_in, const int* in_sizes, int n_in,
                              void* d_out, int out_size, void* d_ws, size_t ws_size,
                              hipStream_t stream)
{
    const float* x  = (const float*)d_in[0];
    const float* Wq = (const float*)d_in[1];
    const float* bq = (const float*)d_in[2];
    const float* Wk = (const float*)d_in[3];
    const float* bk = (const float*)d_in[4];
    const float* Wv = (const float*)d_in[5];
    const float* bv = (const float*)d_in[6];
    const float* Wo = (const float*)d_in[7];
    const float* bo = (const float*)d_in[8];

    const int M = 4096, D = 768;
    const size_t XE = (size_t)M * D;     // 3,145,728
    const size_t WE = (size_t)D * D;     //   589,824

    ushort* xb   = (ushort*)d_ws;
    ushort* wtq  = xb   + XE;            // wtq/wtk/wtv/wto contiguous
    ushort* wto  = wtq  + 3 * WE;
    ushort* qb   = wto  + WE;            // qb/kb/vb contiguous
    ushort* kb   = qb   + XE;
    ushort* vb   = kb   + XE;
    ushort* ctxb = vb   + XE;
    ushort* vt   = xb;                   // reuse xb (dead after fused GEMM)

    cast_f32_bf16<<<(int)(XE / 4 / 256), 256, 0, stream>>>(x, xb, (int)(XE / 4));

    transpose_cast_w4<<<dim3(12, 12, 4), 256, 0, stream>>>(Wq, Wk, Wv, Wo, wtq);

    gemm_qkv_fused<<<dim3(2304 / 128, 4096 / 128), 256, 0, stream>>>(
        xb, wtq, bq, bk, bv, qb);

    transpose_v<<<dim3(32, 12, 2), 256, 0, stream>>>(vb, vt);

    attn_mfma<<<dim3(2048 / 64, 12, 2), 256, 0, stream>>>(qb, kb, vt, ctxb);

    gemm_wo_128<<<dim3(768 / 128, 4096 / 128), 256, 0, stream>>>(
        ctxb, wto, bo, (float*)d_out);
}

// Round 13
// 194.174 us; speedup vs baseline: 1.0671x; 1.0086x over previous
//
#include <hip/hip_runtime.h>
#include <hip/hip_bf16.h>

// ---------------------------------------------------------------------------
// B=2, S=2048, D=768, H=12, Dh=64. M = B*S = 4096.
// R13: R12 (best build: 195.8 us) + XCD-clustered attn grid. All 32
// q-tile blocks of one (b,h) share an XCD -> its K/VT (0.5 MB) stays in
// that XCD's 4MB L2 instead of being re-fetched by 8 XCDs (FETCH 52 MB
// vs ~19 MB compulsory). Decode: idx=xcd+8*slot, pair=(slot/32)*8+xcd.
// Work per block bit-identical; placement is a perf heuristic only (G16).
// ---------------------------------------------------------------------------

typedef __attribute__((ext_vector_type(8))) short short8;   // 8 x bf16 (4 VGPR)
typedef __attribute__((ext_vector_type(4))) float float4e;  // 4 x fp32 acc

__device__ __forceinline__ ushort f2bf(float f) {
    union { float f; unsigned u; } v; v.f = f;
    unsigned r = v.u + 0x7FFF + ((v.u >> 16) & 1);
    return (ushort)(r >> 16);
}

// packed RNE fp32x2 -> bf16x2 (v_cvt_pk_bf16_f32); low 16 bits = first arg
__device__ __forceinline__ unsigned pk2bf(float a, float b) {
    float2 t; t.x = a; t.y = b;
    __hip_bfloat162 h = __float22bfloat162_rn(t);
    union { __hip_bfloat162 h; unsigned u; } cv; cv.h = h;
    return cv.u;
}

// async 16B global -> LDS; LDS dest = wave-uniform base + lane*16.
__device__ __forceinline__ void async_cp16(const ushort* g, ushort* l) {
    __builtin_amdgcn_global_load_lds(
        (const __attribute__((address_space(1))) unsigned int*)g,
        (__attribute__((address_space(3))) unsigned int*)l,
        16, 0, 0);
}

// ===========================================================================
// x [4096x768] fp32 -> bf16
// ===========================================================================
__global__ __launch_bounds__(256) void cast_f32_bf16(
    const float* __restrict__ in, ushort* __restrict__ out, int n4)
{
    int i = blockIdx.x * blockDim.x + threadIdx.x;
    if (i < n4) {
        float4 v = *(const float4*)&in[(size_t)i * 4];
        ushort4 o;
        o.x = f2bf(v.x); o.y = f2bf(v.y); o.z = f2bf(v.z); o.w = f2bf(v.w);
        *(ushort4*)&out[(size_t)i * 4] = o;
    }
}

// ===========================================================================
// All 4 weight transposes in one launch: z selects Wq/Wk/Wv/Wo.
// ===========================================================================
__global__ __launch_bounds__(256) void transpose_cast_w4(
    const float* __restrict__ W0, const float* __restrict__ W1,
    const float* __restrict__ W2, const float* __restrict__ W3,
    ushort* __restrict__ WtBase)
{
    __shared__ float t[64][65];
    const int z = blockIdx.z;
    const float* W = (z == 0) ? W0 : (z == 1) ? W1 : (z == 2) ? W2 : W3;
    ushort* Wt = WtBase + (size_t)z * (768u * 768u);

    const int tid = threadIdx.x;
    const int c  = tid & 63;
    const int rg = tid >> 6;
    const int k0 = blockIdx.y * 64, n0 = blockIdx.x * 64;
    #pragma unroll
    for (int r = 0; r < 16; ++r) {
        const int row = rg * 16 + r;
        t[row][c] = W[(size_t)(k0 + row) * 768 + n0 + c];
    }
    __syncthreads();
    #pragma unroll
    for (int r = 0; r < 16; ++r) {
        const int row = rg * 16 + r;
        Wt[(size_t)(n0 + row) * 768 + k0 + c] = f2bf(t[c][row]);
    }
}

// ===========================================================================
// V [4096x768] bf16 -> VT[b][h][d][s] bf16 (s-major per head).
// ===========================================================================
__global__ __launch_bounds__(256) void transpose_v(
    const ushort* __restrict__ Vb, ushort* __restrict__ VT)
{
    __shared__ ushort t[64][72];
    const int tid = threadIdx.x;
    const int b = blockIdx.z, h = blockIdx.y, s0 = blockIdx.x * 64;
    const int lr = tid >> 3;          // 0..31
    const int lc = (tid & 7) * 8;     // 0..56

    #pragma unroll
    for (int half = 0; half < 64; half += 32) {
        const int row = lr + half;
        *(uint4*)&t[row][lc] =
            *(const uint4*)&Vb[(size_t)(b * 2048 + s0 + row) * 768 + h * 64 + lc];
    }
    __syncthreads();
    #pragma unroll
    for (int half = 0; half < 64; half += 32) {
        const int d = lr + half;
        ushort tmp[8];
        #pragma unroll
        for (int i = 0; i < 8; ++i) tmp[i] = t[lc + i][d];
        *(uint4*)&VT[((size_t)(b * 12 + h) * 64 + d) * 2048 + s0 + lc] =
            *(const uint4*)tmp;
    }
}

// ===========================================================================
// Fused QKV GEMM: Out[M,2304] = x[M,768] @ [Wq|Wk|Wv]^T + [bq|bk|bv]
// 128x128 tile, BK=32, 4 waves 2x2, 16 accs/wave; m97-style async staging.
// ===========================================================================
__global__ __launch_bounds__(256) void gemm_qkv_fused(
    const ushort* __restrict__ A, const ushort* __restrict__ Bt,
    const float* __restrict__ bq, const float* __restrict__ bk,
    const float* __restrict__ bv, ushort* __restrict__ Outbase)
{
    constexpr int K = 768;
    __shared__ ushort As[128][32];   // unpadded: required by global_load_lds
    __shared__ ushort Bs[128][32];

    const int tid  = threadIdx.x;
    const int w    = tid >> 6;
    const int lane = tid & 63;
    const int l16  = lane & 15;
    const int quad = lane >> 4;
    const int wr   = (w >> 1) * 64;
    const int wc   = (w & 1) * 64;
    const int row0 = blockIdx.y * 128, col0 = blockIdx.x * 128;

    const int r4 = lane >> 2;
    const int c8 = (lane & 3) * 8;

    float4e acc[4][4];
    #pragma unroll
    for (int mi = 0; mi < 4; ++mi)
        #pragma unroll
        for (int ni = 0; ni < 4; ++ni) acc[mi][ni] = (float4e){0.f,0.f,0.f,0.f};

    for (int k0 = 0; k0 < K; k0 += 32) {
        #pragma unroll
        for (int i = 0; i < 2; ++i) {
            const int rr = w * 32 + i * 16;
            async_cp16(&A [(size_t)(row0 + rr + r4) * K + k0 + c8], &As[rr][0]);
            async_cp16(&Bt[(size_t)(col0 + rr + r4) * K + k0 + c8], &Bs[rr][0]);
        }
        __syncthreads();   // drains vmcnt -> staged data visible

        short8 af[4], bf[4];
        #pragma unroll
        for (int i = 0; i < 4; ++i) {
            af[i] = *(const short8*)&As[wr + i * 16 + l16][quad * 8];
            bf[i] = *(const short8*)&Bs[wc + i * 16 + l16][quad * 8];
        }
        #pragma unroll
        for (int mi = 0; mi < 4; ++mi)
            #pragma unroll
            for (int ni = 0; ni < 4; ++ni)
                acc[mi][ni] = __builtin_amdgcn_mfma_f32_16x16x32_bf16(
                    af[mi], bf[ni], acc[mi][ni], 0, 0, 0);
        __syncthreads();
    }

    const int seg = (col0 >= 1536) ? 2 : (col0 >= 768 ? 1 : 0);
    const float* bias = (seg == 0) ? bq : (seg == 1) ? bk : bv;
    const int ncol0 = col0 - seg * 768 + wc;
    ushort* outp = Outbase + (size_t)seg * (4096u * 768u);

    #pragma unroll
    for (int ni = 0; ni < 4; ++ni) {
        const int col = ncol0 + ni * 16 + l16;
        const float bs = bias[col];
        #pragma unroll
        for (int mi = 0; mi < 4; ++mi) {
            #pragma unroll
            for (int r = 0; r < 4; ++r) {
                const int row = row0 + wr + mi * 16 + quad * 4 + r;
                outp[(size_t)row * 768 + col] = f2bf(acc[mi][ni][r] + bs);
            }
        }
    }
}

// ===========================================================================
// Wo GEMM: C[4096,768](fp32) = ctx[4096,768] @ Wo^T + bo. 128x128 tile,
// register-prefetch staging.
// ===========================================================================
__global__ __launch_bounds__(256) void gemm_wo_128(
    const ushort* __restrict__ A, const ushort* __restrict__ Bt,
    const float* __restrict__ bias, float* __restrict__ Cout)
{
    constexpr int K = 768, N = 768;
    __shared__ ushort As[128][40];
    __shared__ ushort Bs[128][40];

    const int tid  = threadIdx.x;
    const int w    = tid >> 6;
    const int lane = tid & 63;
    const int l16  = lane & 15;
    const int quad = lane >> 4;
    const int wr   = (w >> 1) * 64;
    const int wc   = (w & 1) * 64;
    const int row0 = blockIdx.y * 128, col0 = blockIdx.x * 128;
    const int sr = tid >> 2, sc = (tid & 3) * 8;

    float4e acc[4][4];
    #pragma unroll
    for (int mi = 0; mi < 4; ++mi)
        #pragma unroll
        for (int ni = 0; ni < 4; ++ni) acc[mi][ni] = (float4e){0.f,0.f,0.f,0.f};

    uint4 a0 = *(const uint4*)&A [(size_t)(row0 + sr     ) * K + sc];
    uint4 a1 = *(const uint4*)&A [(size_t)(row0 + sr + 64) * K + sc];
    uint4 b0 = *(const uint4*)&Bt[(size_t)(col0 + sr     ) * K + sc];
    uint4 b1 = *(const uint4*)&Bt[(size_t)(col0 + sr + 64) * K + sc];

    for (int k0 = 0; k0 < K; k0 += 32) {
        *(uint4*)&As[sr     ][sc] = a0;
        *(uint4*)&As[sr + 64][sc] = a1;
        *(uint4*)&Bs[sr     ][sc] = b0;
        *(uint4*)&Bs[sr + 64][sc] = b1;
        __syncthreads();

        if (k0 + 32 < K) {
            const int kn = k0 + 32;
            a0 = *(const uint4*)&A [(size_t)(row0 + sr     ) * K + kn + sc];
            a1 = *(const uint4*)&A [(size_t)(row0 + sr + 64) * K + kn + sc];
            b0 = *(const uint4*)&Bt[(size_t)(col0 + sr     ) * K + kn + sc];
            b1 = *(const uint4*)&Bt[(size_t)(col0 + sr + 64) * K + kn + sc];
        }

        short8 af[4], bf[4];
        #pragma unroll
        for (int i = 0; i < 4; ++i) {
            af[i] = *(const short8*)&As[wr + i * 16 + l16][quad * 8];
            bf[i] = *(const short8*)&Bs[wc + i * 16 + l16][quad * 8];
        }
        #pragma unroll
        for (int mi = 0; mi < 4; ++mi)
            #pragma unroll
            for (int ni = 0; ni < 4; ++ni)
                acc[mi][ni] = __builtin_amdgcn_mfma_f32_16x16x32_bf16(
                    af[mi], bf[ni], acc[mi][ni], 0, 0, 0);
        __syncthreads();
    }

    #pragma unroll
    for (int ni = 0; ni < 4; ++ni) {
        const int col = col0 + wc + ni * 16 + l16;
        const float bs = bias[col];
        #pragma unroll
        for (int mi = 0; mi < 4; ++mi) {
            #pragma unroll
            for (int r = 0; r < 4; ++r) {
                const int row = row0 + wr + mi * 16 + quad * 4 + r;
                Cout[(size_t)row * N + col] = acc[mi][ni][r] + bs;
            }
        }
    }
}

// ===========================================================================
// Flash attention, S^T formulation, TK=64, packed-cvt (R12 body).
// R13: 1-D grid 768 with XCD-clustered decode — all 32 q-tiles of one
// (b,h) get indices ≡ same residue mod 8 -> same XCD -> K/VT L2-resident.
// ===========================================================================
__global__ __launch_bounds__(256) void attn_mfma(
    const ushort* __restrict__ Qg, const ushort* __restrict__ Kgl,
    const ushort* __restrict__ VT, ushort* __restrict__ Ctx)
{
    constexpr int S = 2048, D = 768;
    __shared__ ushort Ks [64][72];   // [key][d]
    __shared__ ushort Vts[64][72];   // [d][key]
    __shared__ ushort Ps [64][72];   // [w*16+query][key]

    // ---- XCD-clustered decode: idx = xcd + 8*slot; slot = pair_local*32+q
    const int idx  = blockIdx.x;          // 0..767
    const int xcd  = idx & 7;
    const int slot = idx >> 3;            // 0..95
    const int pair = (slot >> 5) * 8 + xcd;   // 0..23, (b,h) pair
    const int q0   = (slot & 31) * 64;
    const int b    = pair / 12;
    const int h    = pair % 12;

    const int tid  = threadIdx.x;
    const int w    = tid >> 6;
    const int lane = tid & 63;
    const int l16  = lane & 15;
    const int quad = lane >> 4;
    const size_t hc = (size_t)h * 64;

    const size_t qoff = (size_t)(b * S + q0 + w * 16 + l16) * D + hc + quad * 8;
    const short8 yq0 = *(const short8*)&Qg[qoff];
    const short8 yq1 = *(const short8*)&Qg[qoff + 32];

    float m_ = -1e30f, l_ = 0.f;
    float4e oa[4];
    #pragma unroll
    for (int n = 0; n < 4; ++n) oa[n] = (float4e){0.f, 0.f, 0.f, 0.f};

    const int sr = tid >> 2;          // key row (Ks) / head-dim (Vts)
    const int sc = (tid & 3) * 16;
    const size_t vtb = ((size_t)(b * 12 + h) * 64 + sr) * 2048;

    uint4 kA, kB, vA, vB;
    {
        const size_t gk = (size_t)(b * S + sr) * D + hc + sc;
        kA = *(const uint4*)&Kgl[gk];
        kB = *(const uint4*)&Kgl[gk + 8];
        vA = *(const uint4*)&VT[vtb + sc];
        vB = *(const uint4*)&VT[vtb + sc + 8];
    }

    for (int k0 = 0; k0 < S; k0 += 64) {
        *(uint4*)&Ks [sr][sc    ] = kA;
        *(uint4*)&Ks [sr][sc + 8] = kB;
        *(uint4*)&Vts[sr][sc    ] = vA;
        *(uint4*)&Vts[sr][sc + 8] = vB;
        __syncthreads();

        if (k0 + 64 < S) {
            const size_t gk = (size_t)(b * S + k0 + 64 + sr) * D + hc + sc;
            kA = *(const uint4*)&Kgl[gk];
            kB = *(const uint4*)&Kgl[gk + 8];
            vA = *(const uint4*)&VT[vtb + k0 + 64 + sc];
            vB = *(const uint4*)&VT[vtb + k0 + 64 + sc + 8];
        }

        // ---- S^T: lane gets S[query=l16][key=kb*16+quad*4+r] ----
        float4e sa[4];
        #pragma unroll
        for (int kb = 0; kb < 4; ++kb) {
            const short8 xk0 = *(const short8*)&Ks[kb * 16 + l16][quad * 8];
            const short8 xk1 = *(const short8*)&Ks[kb * 16 + l16][32 + quad * 8];
            float4e z = (float4e){0.f, 0.f, 0.f, 0.f};
            z      = __builtin_amdgcn_mfma_f32_16x16x32_bf16(xk0, yq0, z, 0, 0, 0);
            sa[kb] = __builtin_amdgcn_mfma_f32_16x16x32_bf16(xk1, yq1, z, 0, 0, 0);
        }

        // ---- online softmax: 16 vals in-lane + 2 cross-quad shuffles ----
        float mx = -1e30f;
        #pragma unroll
        for (int kb = 0; kb < 4; ++kb)
            #pragma unroll
            for (int r = 0; r < 4; ++r) mx = fmaxf(mx, sa[kb][r]);
        mx = fmaxf(mx, __shfl_xor(mx, 16, 64));
        mx = fmaxf(mx, __shfl_xor(mx, 32, 64));
        const float mn = fmaxf(m_, mx);
        const float alpha = __expf(m_ - mn);    // first iter: 0
        float p[4][4], ps = 0.f;
        #pragma unroll
        for (int kb = 0; kb < 4; ++kb)
            #pragma unroll
            for (int r = 0; r < 4; ++r) {
                p[kb][r] = __expf(sa[kb][r] - mn);
                ps += p[kb][r];
            }
        ps += __shfl_xor(ps, 16, 64);
        ps += __shfl_xor(ps, 32, 64);
        l_ = l_ * alpha + ps;
        m_ = mn;

        // ---- P -> LDS: packed cvt, 4 keys per 8B write ----
        #pragma unroll
        for (int kb = 0; kb < 4; ++kb) {
            uint2 pk;
            pk.x = pk2bf(p[kb][0], p[kb][1]);
            pk.y = pk2bf(p[kb][2], p[kb][3]);
            *(uint2*)&Ps[w * 16 + l16][kb * 16 + quad * 4] = pk;
        }

        // ---- rescale O^T and accumulate PV ----
        #pragma unroll
        for (int n = 0; n < 4; ++n)
            #pragma unroll
            for (int r = 0; r < 4; ++r) oa[n][r] *= alpha;

        const short8 yp0 = *(const short8*)&Ps[w * 16 + l16][quad * 8];
        const short8 yp1 = *(const short8*)&Ps[w * 16 + l16][32 + quad * 8];
        #pragma unroll
        for (int db = 0; db < 4; ++db) {
            const short8 xv0 = *(const short8*)&Vts[db * 16 + l16][quad * 8];
            const short8 xv1 = *(const short8*)&Vts[db * 16 + l16][32 + quad * 8];
            oa[db] = __builtin_amdgcn_mfma_f32_16x16x32_bf16(xv0, yp0, oa[db], 0, 0, 0);
            oa[db] = __builtin_amdgcn_mfma_f32_16x16x32_bf16(xv1, yp1, oa[db], 0, 0, 0);
        }
        __syncthreads();
    }

    // ---- normalize, write ctx (packed cvt) ----
    const float inv = 1.0f / l_;
    const size_t crow = (size_t)(b * S + q0 + w * 16 + l16) * D + hc;
    #pragma unroll
    for (int db = 0; db < 4; ++db) {
        uint2 ov;
        ov.x = pk2bf(oa[db][0] * inv, oa[db][1] * inv);
        ov.y = pk2bf(oa[db][2] * inv, oa[db][3] * inv);
        *(uint2*)&Ctx[crow + db * 16 + quad * 4] = ov;
    }
}

// ===========================================================================
// Launch
// ===========================================================================
extern "C" void kernel_launch(void* const* d_in, const int* in_sizes, int n_in,
                              void* d_out, int out_size, void* d_ws, size_t ws_size,
                              hipStream_t stream)
{
    const float* x  = (const float*)d_in[0];
    const float* Wq = (const float*)d_in[1];
    const float* bq = (const float*)d_in[2];
    const float* Wk = (const float*)d_in[3];
    const float* bk = (const float*)d_in[4];
    const float* Wv = (const float*)d_in[5];
    const float* bv = (const float*)d_in[6];
    const float* Wo = (const float*)d_in[7];
    const float* bo = (const float*)d_in[8];

    const int M = 4096, D = 768;
    const size_t XE = (size_t)M * D;     // 3,145,728
    const size_t WE = (size_t)D * D;     //   589,824

    ushort* xb   = (ushort*)d_ws;
    ushort* wtq  = xb   + XE;            // wtq/wtk/wtv/wto contiguous
    ushort* wto  = wtq  + 3 * WE;
    ushort* qb   = wto  + WE;            // qb/kb/vb contiguous
    ushort* kb   = qb   + XE;
    ushort* vb   = kb   + XE;
    ushort* ctxb = vb   + XE;
    ushort* vt   = xb;                   // reuse xb (dead after fused GEMM)

    cast_f32_bf16<<<(int)(XE / 4 / 256), 256, 0, stream>>>(x, xb, (int)(XE / 4));

    transpose_cast_w4<<<dim3(12, 12, 4), 256, 0, stream>>>(Wq, Wk, Wv, Wo, wtq);

    gemm_qkv_fused<<<dim3(2304 / 128, 4096 / 128), 256, 0, stream>>>(
        xb, wtq, bq, bk, bv, qb);

    transpose_v<<<dim3(32, 12, 2), 256, 0, stream>>>(vb, vt);

    attn_mfma<<<768, 256, 0, stream>>>(qb, kb, vt, ctxb);

    gemm_wo_128<<<dim3(768 / 128, 4096 / 128), 256, 0, stream>>>(
        ctxb, wto, bo, (float*)d_out);
}

// Round 14
// 190.516 us; speedup vs baseline: 1.0876x; 1.0192x over previous
//
#include <hip/hip_runtime.h>
#include <hip/hip_bf16.h>

// ---------------------------------------------------------------------------
// B=2, S=2048, D=768, H=12, Dh=64. M = B*S = 4096.
// R14: intra-block split-K attention. 512-thread blocks (8 waves); wave
// pairs (w, w+4) share 16 queries, split each 64-key tile (koff 0/32),
// keep private online (m,l,O); final in-LDS combine. 24 waves/CU (vs 12)
// attacks the measured latency-bound plateau (R13: FETCH 52->9 MB changed
// nothing -> not BW-bound; LDS 45%/VALU 48%/MFMA 15% at 3 blocks/CU).
// Non-attn parts = R12 verbatim (best: 195.8 us).
// ---------------------------------------------------------------------------

typedef __attribute__((ext_vector_type(8))) short short8;   // 8 x bf16 (4 VGPR)
typedef __attribute__((ext_vector_type(4))) float float4e;  // 4 x fp32 acc

__device__ __forceinline__ ushort f2bf(float f) {
    union { float f; unsigned u; } v; v.f = f;
    unsigned r = v.u + 0x7FFF + ((v.u >> 16) & 1);
    return (ushort)(r >> 16);
}

// packed RNE fp32x2 -> bf16x2 (v_cvt_pk_bf16_f32); low 16 bits = first arg
__device__ __forceinline__ unsigned pk2bf(float a, float b) {
    float2 t; t.x = a; t.y = b;
    __hip_bfloat162 h = __float22bfloat162_rn(t);
    union { __hip_bfloat162 h; unsigned u; } cv; cv.h = h;
    return cv.u;
}

// async 16B global -> LDS; LDS dest = wave-uniform base + lane*16.
__device__ __forceinline__ void async_cp16(const ushort* g, ushort* l) {
    __builtin_amdgcn_global_load_lds(
        (const __attribute__((address_space(1))) unsigned int*)g,
        (__attribute__((address_space(3))) unsigned int*)l,
        16, 0, 0);
}

// ===========================================================================
// x [4096x768] fp32 -> bf16
// ===========================================================================
__global__ __launch_bounds__(256) void cast_f32_bf16(
    const float* __restrict__ in, ushort* __restrict__ out, int n4)
{
    int i = blockIdx.x * blockDim.x + threadIdx.x;
    if (i < n4) {
        float4 v = *(const float4*)&in[(size_t)i * 4];
        ushort4 o;
        o.x = f2bf(v.x); o.y = f2bf(v.y); o.z = f2bf(v.z); o.w = f2bf(v.w);
        *(ushort4*)&out[(size_t)i * 4] = o;
    }
}

// ===========================================================================
// All 4 weight transposes in one launch: z selects Wq/Wk/Wv/Wo.
// ===========================================================================
__global__ __launch_bounds__(256) void transpose_cast_w4(
    const float* __restrict__ W0, const float* __restrict__ W1,
    const float* __restrict__ W2, const float* __restrict__ W3,
    ushort* __restrict__ WtBase)
{
    __shared__ float t[64][65];
    const int z = blockIdx.z;
    const float* W = (z == 0) ? W0 : (z == 1) ? W1 : (z == 2) ? W2 : W3;
    ushort* Wt = WtBase + (size_t)z * (768u * 768u);

    const int tid = threadIdx.x;
    const int c  = tid & 63;
    const int rg = tid >> 6;
    const int k0 = blockIdx.y * 64, n0 = blockIdx.x * 64;
    #pragma unroll
    for (int r = 0; r < 16; ++r) {
        const int row = rg * 16 + r;
        t[row][c] = W[(size_t)(k0 + row) * 768 + n0 + c];
    }
    __syncthreads();
    #pragma unroll
    for (int r = 0; r < 16; ++r) {
        const int row = rg * 16 + r;
        Wt[(size_t)(n0 + row) * 768 + k0 + c] = f2bf(t[c][row]);
    }
}

// ===========================================================================
// V [4096x768] bf16 -> VT[b][h][d][s] bf16 (s-major per head).
// ===========================================================================
__global__ __launch_bounds__(256) void transpose_v(
    const ushort* __restrict__ Vb, ushort* __restrict__ VT)
{
    __shared__ ushort t[64][72];
    const int tid = threadIdx.x;
    const int b = blockIdx.z, h = blockIdx.y, s0 = blockIdx.x * 64;
    const int lr = tid >> 3;          // 0..31
    const int lc = (tid & 7) * 8;     // 0..56

    #pragma unroll
    for (int half = 0; half < 64; half += 32) {
        const int row = lr + half;
        *(uint4*)&t[row][lc] =
            *(const uint4*)&Vb[(size_t)(b * 2048 + s0 + row) * 768 + h * 64 + lc];
    }
    __syncthreads();
    #pragma unroll
    for (int half = 0; half < 64; half += 32) {
        const int d = lr + half;
        ushort tmp[8];
        #pragma unroll
        for (int i = 0; i < 8; ++i) tmp[i] = t[lc + i][d];
        *(uint4*)&VT[((size_t)(b * 12 + h) * 64 + d) * 2048 + s0 + lc] =
            *(const uint4*)tmp;
    }
}

// ===========================================================================
// Fused QKV GEMM: Out[M,2304] = x[M,768] @ [Wq|Wk|Wv]^T + [bq|bk|bv]
// 128x128 tile, BK=32, 4 waves 2x2, 16 accs/wave; m97-style async staging.
// ===========================================================================
__global__ __launch_bounds__(256) void gemm_qkv_fused(
    const ushort* __restrict__ A, const ushort* __restrict__ Bt,
    const float* __restrict__ bq, const float* __restrict__ bk,
    const float* __restrict__ bv, ushort* __restrict__ Outbase)
{
    constexpr int K = 768;
    __shared__ ushort As[128][32];   // unpadded: required by global_load_lds
    __shared__ ushort Bs[128][32];

    const int tid  = threadIdx.x;
    const int w    = tid >> 6;
    const int lane = tid & 63;
    const int l16  = lane & 15;
    const int quad = lane >> 4;
    const int wr   = (w >> 1) * 64;
    const int wc   = (w & 1) * 64;
    const int row0 = blockIdx.y * 128, col0 = blockIdx.x * 128;

    const int r4 = lane >> 2;
    const int c8 = (lane & 3) * 8;

    float4e acc[4][4];
    #pragma unroll
    for (int mi = 0; mi < 4; ++mi)
        #pragma unroll
        for (int ni = 0; ni < 4; ++ni) acc[mi][ni] = (float4e){0.f,0.f,0.f,0.f};

    for (int k0 = 0; k0 < K; k0 += 32) {
        #pragma unroll
        for (int i = 0; i < 2; ++i) {
            const int rr = w * 32 + i * 16;
            async_cp16(&A [(size_t)(row0 + rr + r4) * K + k0 + c8], &As[rr][0]);
            async_cp16(&Bt[(size_t)(col0 + rr + r4) * K + k0 + c8], &Bs[rr][0]);
        }
        __syncthreads();   // drains vmcnt -> staged data visible

        short8 af[4], bf[4];
        #pragma unroll
        for (int i = 0; i < 4; ++i) {
            af[i] = *(const short8*)&As[wr + i * 16 + l16][quad * 8];
            bf[i] = *(const short8*)&Bs[wc + i * 16 + l16][quad * 8];
        }
        #pragma unroll
        for (int mi = 0; mi < 4; ++mi)
            #pragma unroll
            for (int ni = 0; ni < 4; ++ni)
                acc[mi][ni] = __builtin_amdgcn_mfma_f32_16x16x32_bf16(
                    af[mi], bf[ni], acc[mi][ni], 0, 0, 0);
        __syncthreads();
    }

    const int seg = (col0 >= 1536) ? 2 : (col0 >= 768 ? 1 : 0);
    const float* bias = (seg == 0) ? bq : (seg == 1) ? bk : bv;
    const int ncol0 = col0 - seg * 768 + wc;
    ushort* outp = Outbase + (size_t)seg * (4096u * 768u);

    #pragma unroll
    for (int ni = 0; ni < 4; ++ni) {
        const int col = ncol0 + ni * 16 + l16;
        const float bs = bias[col];
        #pragma unroll
        for (int mi = 0; mi < 4; ++mi) {
            #pragma unroll
            for (int r = 0; r < 4; ++r) {
                const int row = row0 + wr + mi * 16 + quad * 4 + r;
                outp[(size_t)row * 768 + col] = f2bf(acc[mi][ni][r] + bs);
            }
        }
    }
}

// ===========================================================================
// Wo GEMM: C[4096,768](fp32) = ctx[4096,768] @ Wo^T + bo. 128x128 tile,
// register-prefetch staging.
// ===========================================================================
__global__ __launch_bounds__(256) void gemm_wo_128(
    const ushort* __restrict__ A, const ushort* __restrict__ Bt,
    const float* __restrict__ bias, float* __restrict__ Cout)
{
    constexpr int K = 768, N = 768;
    __shared__ ushort As[128][40];
    __shared__ ushort Bs[128][40];

    const int tid  = threadIdx.x;
    const int w    = tid >> 6;
    const int lane = tid & 63;
    const int l16  = lane & 15;
    const int quad = lane >> 4;
    const int wr   = (w >> 1) * 64;
    const int wc   = (w & 1) * 64;
    const int row0 = blockIdx.y * 128, col0 = blockIdx.x * 128;
    const int sr = tid >> 2, sc = (tid & 3) * 8;

    float4e acc[4][4];
    #pragma unroll
    for (int mi = 0; mi < 4; ++mi)
        #pragma unroll
        for (int ni = 0; ni < 4; ++ni) acc[mi][ni] = (float4e){0.f,0.f,0.f,0.f};

    uint4 a0 = *(const uint4*)&A [(size_t)(row0 + sr     ) * K + sc];
    uint4 a1 = *(const uint4*)&A [(size_t)(row0 + sr + 64) * K + sc];
    uint4 b0 = *(const uint4*)&Bt[(size_t)(col0 + sr     ) * K + sc];
    uint4 b1 = *(const uint4*)&Bt[(size_t)(col0 + sr + 64) * K + sc];

    for (int k0 = 0; k0 < K; k0 += 32) {
        *(uint4*)&As[sr     ][sc] = a0;
        *(uint4*)&As[sr + 64][sc] = a1;
        *(uint4*)&Bs[sr     ][sc] = b0;
        *(uint4*)&Bs[sr + 64][sc] = b1;
        __syncthreads();

        if (k0 + 32 < K) {
            const int kn = k0 + 32;
            a0 = *(const uint4*)&A [(size_t)(row0 + sr     ) * K + kn + sc];
            a1 = *(const uint4*)&A [(size_t)(row0 + sr + 64) * K + kn + sc];
            b0 = *(const uint4*)&Bt[(size_t)(col0 + sr     ) * K + kn + sc];
            b1 = *(const uint4*)&Bt[(size_t)(col0 + sr + 64) * K + kn + sc];
        }

        short8 af[4], bf[4];
        #pragma unroll
        for (int i = 0; i < 4; ++i) {
            af[i] = *(const short8*)&As[wr + i * 16 + l16][quad * 8];
            bf[i] = *(const short8*)&Bs[wc + i * 16 + l16][quad * 8];
        }
        #pragma unroll
        for (int mi = 0; mi < 4; ++mi)
            #pragma unroll
            for (int ni = 0; ni < 4; ++ni)
                acc[mi][ni] = __builtin_amdgcn_mfma_f32_16x16x32_bf16(
                    af[mi], bf[ni], acc[mi][ni], 0, 0, 0);
        __syncthreads();
    }

    #pragma unroll
    for (int ni = 0; ni < 4; ++ni) {
        const int col = col0 + wc + ni * 16 + l16;
        const float bs = bias[col];
        #pragma unroll
        for (int mi = 0; mi < 4; ++mi) {
            #pragma unroll
            for (int r = 0; r < 4; ++r) {
                const int row = row0 + wr + mi * 16 + quad * 4 + r;
                Cout[(size_t)row * N + col] = acc[mi][ni][r] + bs;
            }
        }
    }
}

// ===========================================================================
// Flash attention, S^T form, intra-block split-K. 512 threads = 8 waves.
// Wave w: query group wq = w&3 (16 queries), key-half koff = (w>>2)*32.
// Each wave keeps private online (m,l,O) over its key-half of every tile;
// waves 4-7 publish (m,l,O) to LDS at the end; waves 0-3 merge and write.
// Per tile per wave: 2 score-chains (4 mfma) + 4 PV mfma over 32 keys.
// LDS: Ks/Vts/Ps 27 KB + Osc 17.4 KB + Msc/Lsc 0.5 KB = 45.5 KB
// -> 3 blocks/CU (grid 768 = 3/CU even) = 24 waves/CU.
// ===========================================================================
__global__ __launch_bounds__(512) void attn_mfma(
    const ushort* __restrict__ Qg, const ushort* __restrict__ Kgl,
    const ushort* __restrict__ VT, ushort* __restrict__ Ctx)
{
    constexpr int S = 2048, D = 768;
    __shared__ ushort Ks [64][72];    // [key][d]
    __shared__ ushort Vts[64][72];    // [d][key]
    __shared__ ushort Ps [64][72];    // [query][key]
    __shared__ float  Osc[4][16][68]; // combine buffer (68: bank spread)
    __shared__ float  Msc[4][16], Lsc[4][16];

    const int tid  = threadIdx.x;
    const int w    = tid >> 6;        // 0..7
    const int wq   = w & 3;           // query group
    const int koff = (w >> 2) * 32;   // key-half within tile
    const int lane = tid & 63;
    const int l16  = lane & 15;
    const int quad = lane >> 4;
    const int b = blockIdx.z, h = blockIdx.y, q0 = blockIdx.x * 64;
    const size_t hc = (size_t)h * 64;

    const size_t qoff = (size_t)(b * S + q0 + wq * 16 + l16) * D + hc + quad * 8;
    const short8 yq0 = *(const short8*)&Qg[qoff];
    const short8 yq1 = *(const short8*)&Qg[qoff + 32];

    float m_ = -1e30f, l_ = 0.f;
    float4e oa[4];
    #pragma unroll
    for (int n = 0; n < 4; ++n) oa[n] = (float4e){0.f, 0.f, 0.f, 0.f};

    // staging: 512 threads, one uint4 each per matrix
    const int sr = tid >> 3;          // 0..63
    const int sc = (tid & 7) * 8;     // 0..56
    const size_t vtb = ((size_t)(b * 12 + h) * 64 + sr) * 2048;

    uint4 kf = *(const uint4*)&Kgl[(size_t)(b * S + sr) * D + hc + sc];
    uint4 vf = *(const uint4*)&VT[vtb + sc];

    for (int k0 = 0; k0 < S; k0 += 64) {
        *(uint4*)&Ks [sr][sc] = kf;
        *(uint4*)&Vts[sr][sc] = vf;
        __syncthreads();

        if (k0 + 64 < S) {
            kf = *(const uint4*)&Kgl[(size_t)(b * S + k0 + 64 + sr) * D + hc + sc];
            vf = *(const uint4*)&VT[vtb + k0 + 64 + sc];
        }

        // ---- scores for this wave's 32 keys: S^T[key][query] ----
        float4e sa[2];
        #pragma unroll
        for (int kb = 0; kb < 2; ++kb) {
            const short8 xk0 = *(const short8*)&Ks[koff + kb * 16 + l16][quad * 8];
            const short8 xk1 = *(const short8*)&Ks[koff + kb * 16 + l16][32 + quad * 8];
            float4e z = (float4e){0.f, 0.f, 0.f, 0.f};
            z      = __builtin_amdgcn_mfma_f32_16x16x32_bf16(xk0, yq0, z, 0, 0, 0);
            sa[kb] = __builtin_amdgcn_mfma_f32_16x16x32_bf16(xk1, yq1, z, 0, 0, 0);
        }

        // ---- private online softmax: 8 in-lane + xor 16,32 ----
        float mx = -1e30f;
        #pragma unroll
        for (int kb = 0; kb < 2; ++kb)
            #pragma unroll
            for (int r = 0; r < 4; ++r) mx = fmaxf(mx, sa[kb][r]);
        mx = fmaxf(mx, __shfl_xor(mx, 16, 64));
        mx = fmaxf(mx, __shfl_xor(mx, 32, 64));
        const float mn = fmaxf(m_, mx);
        const float alpha = __expf(m_ - mn);    // first iter: 0
        float p[2][4], ps = 0.f;
        #pragma unroll
        for (int kb = 0; kb < 2; ++kb)
            #pragma unroll
            for (int r = 0; r < 4; ++r) {
                p[kb][r] = __expf(sa[kb][r] - mn);
                ps += p[kb][r];
            }
        ps += __shfl_xor(ps, 16, 64);
        ps += __shfl_xor(ps, 32, 64);
        l_ = l_ * alpha + ps;
        m_ = mn;

        // ---- P -> LDS (own key-half columns; wave-private r/w) ----
        #pragma unroll
        for (int kb = 0; kb < 2; ++kb) {
            uint2 pk;
            pk.x = pk2bf(p[kb][0], p[kb][1]);
            pk.y = pk2bf(p[kb][2], p[kb][3]);
            *(uint2*)&Ps[wq * 16 + l16][koff + kb * 16 + quad * 4] = pk;
        }

        // ---- rescale O^T, PV over own 32 keys (one mfma per db) ----
        #pragma unroll
        for (int n = 0; n < 4; ++n)
            #pragma unroll
            for (int r = 0; r < 4; ++r) oa[n][r] *= alpha;

        const short8 yp = *(const short8*)&Ps[wq * 16 + l16][koff + quad * 8];
        #pragma unroll
        for (int db = 0; db < 4; ++db) {
            const short8 xv = *(const short8*)&Vts[db * 16 + l16][koff + quad * 8];
            oa[db] = __builtin_amdgcn_mfma_f32_16x16x32_bf16(xv, yp, oa[db], 0, 0, 0);
        }
        __syncthreads();
    }

    // ---- intra-block split-K combine ----
    if (w >= 4) {
        if (quad == 0) { Msc[wq][l16] = m_; Lsc[wq][l16] = l_; }
        #pragma unroll
        for (int db = 0; db < 4; ++db)
            *(float4*)&Osc[wq][l16][db * 16 + quad * 4] =
                *(const float4*)&oa[db];
    }
    __syncthreads();
    if (w < 4) {
        const float m1 = Msc[wq][l16], l1 = Lsc[wq][l16];
        const float mm = fmaxf(m_, m1);
        const float a0 = __expf(m_ - mm), a1 = __expf(m1 - mm);
        const float inv = 1.0f / (l_ * a0 + l1 * a1);
        const size_t crow = (size_t)(b * S + q0 + wq * 16 + l16) * D + hc;
        #pragma unroll
        for (int db = 0; db < 4; ++db) {
            const float4 o1 = *(const float4*)&Osc[wq][l16][db * 16 + quad * 4];
            uint2 ov;
            ov.x = pk2bf((oa[db][0] * a0 + o1.x * a1) * inv,
                         (oa[db][1] * a0 + o1.y * a1) * inv);
            ov.y = pk2bf((oa[db][2] * a0 + o1.z * a1) * inv,
                         (oa[db][3] * a0 + o1.w * a1) * inv);
            *(uint2*)&Ctx[crow + db * 16 + quad * 4] = ov;
        }
    }
}

// ===========================================================================
// Launch
// ===========================================================================
extern "C" void kernel_launch(void* const* d_in, const int* in_sizes, int n_in,
                              void* d_out, int out_size, void* d_ws, size_t ws_size,
                              hipStream_t stream)
{
    const float* x  = (const float*)d_in[0];
    const float* Wq = (const float*)d_in[1];
    const float* bq = (const float*)d_in[2];
    const float* Wk = (const float*)d_in[3];
    const float* bk = (const float*)d_in[4];
    const float* Wv = (const float*)d_in[5];
    const float* bv = (const float*)d_in[6];
    const float* Wo = (const float*)d_in[7];
    const float* bo = (const float*)d_in[8];

    const int M = 4096, D = 768;
    const size_t XE = (size_t)M * D;     // 3,145,728
    const size_t WE = (size_t)D * D;     //   589,824

    ushort* xb   = (ushort*)d_ws;
    ushort* wtq  = xb   + XE;            // wtq/wtk/wtv/wto contiguous
    ushort* wto  = wtq  + 3 * WE;
    ushort* qb   = wto  + WE;            // qb/kb/vb contiguous
    ushort* kb   = qb   + XE;
    ushort* vb   = kb   + XE;
    ushort* ctxb = vb   + XE;
    ushort* vt   = xb;                   // reuse xb (dead after fused GEMM)

    cast_f32_bf16<<<(int)(XE / 4 / 256), 256, 0, stream>>>(x, xb, (int)(XE / 4));

    transpose_cast_w4<<<dim3(12, 12, 4), 256, 0, stream>>>(Wq, Wk, Wv, Wo, wtq);

    gemm_qkv_fused<<<dim3(2304 / 128, 4096 / 128), 256, 0, stream>>>(
        xb, wtq, bq, bk, bv, qb);

    transpose_v<<<dim3(32, 12, 2), 256, 0, stream>>>(vb, vt);

    attn_mfma<<<dim3(2048 / 64, 12, 2), 512, 0, stream>>>(qb, kb, vt, ctxb);

    gemm_wo_128<<<dim3(768 / 128, 4096 / 128), 256, 0, stream>>>(
        ctxb, wto, bo, (float*)d_out);
}